// Round 3
// baseline (120.634 us; speedup 1.0000x reference)
//
#include <hip/hip_runtime.h>
#include <hip/hip_fp16.h>
#include <stdint.h>

#define D0 1024
#define D1 8192
#define D2 8192
#define D3 10240
#define NGATES (D1 + D2 + D3)   // 26624
#define B_ROWS 4096

// k1 LDS: h1 at 0 (zero-add stage-C gathers), xb after. 72 KB -> 2 blocks/CU.
#define SM1_H1    0
#define SM1_XB    65536
#define SM1_BYTES 73728
// k2 LDS: h2 at 0 (zero-add stage-D gathers) + csum. 64.2 KB -> 2 blocks/CU.
#define SM2_CSUM  65536
#define SM2_BYTES (65536 + 160)

// Pre-pass: per gate, softmax(w[16]) @ OP_COEF -> 4 coefs stored as
// half2-DUPLICATED uint4 (c0c0,c1c1,c2c2,c3c3); gather indices as PRE-SCALED
// byte offsets (ia*8)|(ib*8)<<16. Row-invariant -> once per launch.
__global__ __launch_bounds__(64) void prep_kernel(
    const float* __restrict__ w1, const float* __restrict__ w2,
    const float* __restrict__ w3,
    const int* __restrict__ ia1, const int* __restrict__ ib1,
    const int* __restrict__ ia2, const int* __restrict__ ib2,
    const int* __restrict__ ia3, const int* __restrict__ ib3,
    uint4* __restrict__ coefb, uint32_t* __restrict__ idxp) {
    int G = blockIdx.x * 64 + threadIdx.x;  // grid is exactly NGATES/64
    const float* w;
    int ia, ib;
    if (G < D1) {
        w = w1 + (size_t)G * 16; ia = ia1[G]; ib = ib1[G];
    } else if (G < D1 + D2) {
        int g = G - D1;
        w = w2 + (size_t)g * 16; ia = ia2[g]; ib = ib2[g];
    } else {
        int g = G - D1 - D2;
        w = w3 + (size_t)g * 16; ia = ia3[g]; ib = ib3[g];
    }
    const float4* wv = (const float4*)w;
    float4 q0 = wv[0], q1 = wv[1], q2 = wv[2], q3 = wv[3];
    float wa[16] = {q0.x, q0.y, q0.z, q0.w, q1.x, q1.y, q1.z, q1.w,
                    q2.x, q2.y, q2.z, q2.w, q3.x, q3.y, q3.z, q3.w};
    float m = wa[0];
#pragma unroll
    for (int i = 1; i < 16; ++i) m = fmaxf(m, wa[i]);
    float e[16], s = 0.f;
#pragma unroll
    for (int i = 0; i < 16; ++i) { e[i] = __expf(wa[i] - m); s += e[i]; }
    float inv = 1.f / s;
    static constexpr float OPC[16][4] = {
        {0.f, 0.f, 0.f, 0.f}, {0.f, 0.f, 0.f, 1.f}, {0.f, 1.f, 0.f, -1.f}, {0.f, 1.f, 0.f, 0.f},
        {0.f, 0.f, 1.f, -1.f}, {0.f, 0.f, 1.f, 0.f}, {0.f, 1.f, 1.f, -2.f}, {0.f, 1.f, 1.f, -1.f},
        {1.f, -1.f, -1.f, 1.f}, {1.f, -1.f, -1.f, 2.f}, {1.f, 0.f, -1.f, 0.f}, {1.f, 0.f, -1.f, 1.f},
        {1.f, -1.f, 0.f, 0.f}, {1.f, -1.f, 0.f, 1.f}, {1.f, 0.f, 0.f, -1.f}, {1.f, 0.f, 0.f, 0.f}};
    float c0 = 0.f, c1 = 0.f, c2 = 0.f, c3 = 0.f;
#pragma unroll
    for (int i = 0; i < 16; ++i) {  // 0/±1/±2 multiplies fold at compile time
        float p = e[i] * inv;
        c0 += p * OPC[i][0];
        c1 += p * OPC[i][1];
        c2 += p * OPC[i][2];
        c3 += p * OPC[i][3];
    }
    uint4 cv;
    cv.x = __builtin_bit_cast(uint32_t, __floats2half2_rn(c0, c0));
    cv.y = __builtin_bit_cast(uint32_t, __floats2half2_rn(c1, c1));
    cv.z = __builtin_bit_cast(uint32_t, __floats2half2_rn(c2, c2));
    cv.w = __builtin_bit_cast(uint32_t, __floats2half2_rn(c3, c3));
    coefb[G] = cv;
    idxp[G] = (uint32_t)(ia << 3) | ((uint32_t)(ib << 3) << 16);
}

// One gate for 4 rows (2x half2), coefs pre-broadcast.
// h = (c0 + c2*b) + a*(c1 + c3*b): 6 v_pk_fma_f16, zero unpack ops.
__device__ __forceinline__ uint2 gate4(uint2 av, uint2 bv, uint4 cf) {
    __half2 a01 = __builtin_bit_cast(__half2, av.x);
    __half2 a23 = __builtin_bit_cast(__half2, av.y);
    __half2 b01 = __builtin_bit_cast(__half2, bv.x);
    __half2 b23 = __builtin_bit_cast(__half2, bv.y);
    __half2 c0 = __builtin_bit_cast(__half2, cf.x);
    __half2 c1 = __builtin_bit_cast(__half2, cf.y);
    __half2 c2 = __builtin_bit_cast(__half2, cf.z);
    __half2 c3 = __builtin_bit_cast(__half2, cf.w);
    __half2 h01 = __hfma2(a01, __hfma2(b01, c3, c1), __hfma2(b01, c2, c0));
    __half2 h23 = __hfma2(a23, __hfma2(b23, c3, c1), __hfma2(b23, c2, c0));
    uint2 r;
    r.x = __builtin_bit_cast(uint32_t, h01);
    r.y = __builtin_bit_cast(uint32_t, h23);
    return r;
}

// k1: layers 1+2 for 4 batch rows/block. h1 in LDS; h2 -> global (fp16,
// [block][gate][4rows], coalesced). 72 KB LDS -> 2 blocks/CU, 32 waves/CU.
__global__ __launch_bounds__(1024, 8) void k1_layers12(
    const float* __restrict__ x, const uint4* __restrict__ coefb,
    const uint32_t* __restrict__ idxp, uint2* __restrict__ h2g) {
    extern __shared__ char sm[];
    uint2* h1 = (uint2*)(sm + SM1_H1);
    uint2* xb = (uint2*)(sm + SM1_XB);

    const int t = threadIdx.x;
    const int rowbase = blockIdx.x << 2;

    // Prefetch stage-B metadata (in flight across stage A + barrier).
    uint32_t pI[8];
    uint4 pC[8];
#pragma unroll
    for (int k = 0; k < 8; ++k) {
        int g = t + (k << 10);
        pI[k] = idxp[g];
        pC[k] = coefb[g];
    }

    // Stage A: 4 rows of x -> fp16, row-interleaved into xb.
    {
        const float* xp = x + (size_t)rowbase * D0 + t;
        float v0 = xp[0];
        float v1 = xp[D0];
        float v2 = xp[2 * D0];
        float v3 = xp[3 * D0];
        uint2 v;
        v.x = __builtin_bit_cast(uint32_t, __floats2half2_rn(v0, v1));
        v.y = __builtin_bit_cast(uint32_t, __floats2half2_rn(v2, v3));
        xb[t] = v;
    }
    __syncthreads();

    // Stage B: layer 1 (gather from xb; packed offsets need +SM1_XB base).
#pragma unroll
    for (int k = 0; k < 8; ++k) {
        int g = t + (k << 10);
        uint32_t ip = pI[k];
        uint2 av = *(const uint2*)(sm + SM1_XB + (ip & 0xffffu));
        uint2 bv = *(const uint2*)(sm + SM1_XB + (ip >> 16));
        h1[g] = gate4(av, bv, pC[k]);
    }
    // Prefetch stage-C metadata before the barrier.
#pragma unroll
    for (int k = 0; k < 8; ++k) {
        int g = D1 + t + (k << 10);
        pI[k] = idxp[g];
        pC[k] = coefb[g];
    }
    __syncthreads();

    // Stage C: layer 2 (gather from h1 at LDS base 0 -> zero-add addressing),
    // results straight to global, coalesced (thread t -> gate t+k*1024).
    uint2* h2out = h2g + ((size_t)blockIdx.x << 13);
#pragma unroll
    for (int k = 0; k < 8; ++k) {
        int g = t + (k << 10);
        uint32_t ip = pI[k];
        uint2 av = *(const uint2*)(sm + (ip & 0xffffu));
        uint2 bv = *(const uint2*)(sm + (ip >> 16));
        h2out[g] = gate4(av, bv, pC[k]);
    }
}

// k2: layer 3 + grouped sum. Copies its block's 64 KB h2 slab into LDS
// (coalesced dwordx4), then stage D. 64.2 KB LDS -> 2 blocks/CU.
__global__ __launch_bounds__(1024, 8) void k2_layer3(
    const uint2* __restrict__ h2g, const uint4* __restrict__ coefb,
    const uint32_t* __restrict__ idxp, float* __restrict__ out) {
    extern __shared__ char sm[];
    float* csum = (float*)(sm + SM2_CSUM);

    const int t = threadIdx.x;
    const int rowbase = blockIdx.x << 2;

    // Load h2 slab: 4096 x uint4, 16 B/lane coalesced.
    {
        uint4* dst = (uint4*)sm;
        const uint4* src = (const uint4*)(h2g + ((size_t)blockIdx.x << 13));
#pragma unroll
        for (int j = 0; j < 4; ++j) dst[t + (j << 10)] = src[t + (j << 10)];
    }
    if (t < 40) csum[t] = 0.f;
    __syncthreads();

    // Stage D: each wave owns 640 contiguous gates (spans <=2 classes;
    // 64-gate chunks never straddle a class boundary: 1024 % 64 == 0).
    {
        const int wv = t >> 6, lane = t & 63;
        const int gbase = wv * 640;
        const int cA = gbase >> 10;
        const int bnd = (cA + 1) << 10;
        float s0[4] = {0.f, 0.f, 0.f, 0.f};
        float s1[4] = {0.f, 0.f, 0.f, 0.f};
#pragma unroll
        for (int j = 0; j < 10; ++j) {
            int gc = gbase + (j << 6);
            int g = D1 + D2 + gc + lane;
            uint32_t ip = idxp[g];
            uint4 cf = coefb[g];
            uint2 av = *(const uint2*)(sm + (ip & 0xffffu));
            uint2 bv = *(const uint2*)(sm + (ip >> 16));
            uint2 hv = gate4(av, bv, cf);
            __half2 h01 = __builtin_bit_cast(__half2, hv.x);
            __half2 h23 = __builtin_bit_cast(__half2, hv.y);
            float f0 = __low2float(h01), f1 = __high2float(h01);
            float f2 = __low2float(h23), f3 = __high2float(h23);
            if (gc < bnd) {
                s0[0] += f0; s0[1] += f1; s0[2] += f2; s0[3] += f3;
            } else {
                s1[0] += f0; s1[1] += f1; s1[2] += f2; s1[3] += f3;
            }
        }
#pragma unroll
        for (int m = 1; m < 64; m <<= 1) {
#pragma unroll
            for (int r = 0; r < 4; ++r) {
                s0[r] += __shfl_xor(s0[r], m, 64);
                s1[r] += __shfl_xor(s1[r], m, 64);
            }
        }
        if (lane == 0) {
#pragma unroll
            for (int r = 0; r < 4; ++r) atomicAdd(&csum[cA * 4 + r], s0[r]);
            if (gbase + 640 > bnd) {
#pragma unroll
                for (int r = 0; r < 4; ++r) atomicAdd(&csum[(cA + 1) * 4 + r], s1[r]);
            }
        }
    }
    __syncthreads();

    if (t < 40) {
        int c = t >> 2, r = t & 3;
        out[(size_t)(rowbase + r) * 10 + c] = csum[t] * (1.0f / 30.0f);
    }
}

extern "C" void kernel_launch(void* const* d_in, const int* in_sizes, int n_in,
                              void* d_out, int out_size, void* d_ws, size_t ws_size,
                              hipStream_t stream) {
    const float* x = (const float*)d_in[0];
    const float* w1 = (const float*)d_in[1];
    const float* w2 = (const float*)d_in[2];
    const float* w3 = (const float*)d_in[3];
    const int* ia1 = (const int*)d_in[4];
    const int* ib1 = (const int*)d_in[5];
    const int* ia2 = (const int*)d_in[6];
    const int* ib2 = (const int*)d_in[7];
    const int* ia3 = (const int*)d_in[8];
    const int* ib3 = (const int*)d_in[9];
    float* out = (float*)d_out;

    // Workspace layout: coefb 26624*16 B | idxp 26624*4 B | h2g 64 MB.
    uint4* coefb = (uint4*)d_ws;
    uint32_t* idxp = (uint32_t*)((char*)d_ws + (size_t)NGATES * 16);
    uint2* h2g = (uint2*)((char*)d_ws + (size_t)NGATES * 20 + 4096);  // keep 8B-aligned slack

    // >64KB dynamic LDS opt-in (host-side; graph-capture safe).
    hipFuncSetAttribute(reinterpret_cast<const void*>(k1_layers12),
                        hipFuncAttributeMaxDynamicSharedMemorySize, SM1_BYTES);
    hipFuncSetAttribute(reinterpret_cast<const void*>(k2_layer3),
                        hipFuncAttributeMaxDynamicSharedMemorySize, SM2_BYTES);

    prep_kernel<<<NGATES / 64, 64, 0, stream>>>(
        w1, w2, w3, ia1, ib1, ia2, ib2, ia3, ib3, coefb, idxp);
    k1_layers12<<<B_ROWS / 4, 1024, SM1_BYTES, stream>>>(x, coefb, idxp, h2g);
    k2_layer3<<<B_ROWS / 4, 1024, SM2_BYTES, stream>>>(h2g, coefb, idxp, out);
}

// Round 4
// 107.141 us; speedup vs baseline: 1.1259x; 1.1259x over previous
//
#include <hip/hip_runtime.h>
#include <hip/hip_fp16.h>
#include <stdint.h>

#define D0 1024
#define D1 8192
#define D2 8192
#define D3 10240
#define B_ROWS 4096

// LDS layout (bytes): xb at 0 (zero-add BC gathers), h2 at 8192 (stage-D
// gathers use the 16-bit ds offset immediate 8192), csum after.
// 72.2 KB -> 2 blocks/CU, 32 waves/CU.
#define SM_XB     0
#define SM_H2     8192
#define SM_CSUM   (8192 + 65536)
#define SM_BYTES  (8192 + 65536 + 160)

// softmax(w[16]) @ OP_COEF -> (c0,c1,c2,c3)
__device__ __forceinline__ float4 softmax_coef(const float* __restrict__ w) {
    const float4* wv = (const float4*)w;
    float4 q0 = wv[0], q1 = wv[1], q2 = wv[2], q3 = wv[3];
    float wa[16] = {q0.x, q0.y, q0.z, q0.w, q1.x, q1.y, q1.z, q1.w,
                    q2.x, q2.y, q2.z, q2.w, q3.x, q3.y, q3.z, q3.w};
    float m = wa[0];
#pragma unroll
    for (int i = 1; i < 16; ++i) m = fmaxf(m, wa[i]);
    float e[16], s = 0.f;
#pragma unroll
    for (int i = 0; i < 16; ++i) { e[i] = __expf(wa[i] - m); s += e[i]; }
    float inv = 1.f / s;
    static constexpr float OPC[16][4] = {
        {0.f, 0.f, 0.f, 0.f}, {0.f, 0.f, 0.f, 1.f}, {0.f, 1.f, 0.f, -1.f}, {0.f, 1.f, 0.f, 0.f},
        {0.f, 0.f, 1.f, -1.f}, {0.f, 0.f, 1.f, 0.f}, {0.f, 1.f, 1.f, -2.f}, {0.f, 1.f, 1.f, -1.f},
        {1.f, -1.f, -1.f, 1.f}, {1.f, -1.f, -1.f, 2.f}, {1.f, 0.f, -1.f, 0.f}, {1.f, 0.f, -1.f, 1.f},
        {1.f, -1.f, 0.f, 0.f}, {1.f, -1.f, 0.f, 1.f}, {1.f, 0.f, 0.f, -1.f}, {1.f, 0.f, 0.f, 0.f}};
    float c0 = 0.f, c1 = 0.f, c2 = 0.f, c3 = 0.f;
#pragma unroll
    for (int i = 0; i < 16; ++i) {  // 0/±1/±2 multiplies fold at compile time
        float p = e[i] * inv;
        c0 += p * OPC[i][0];
        c1 += p * OPC[i][1];
        c2 += p * OPC[i][2];
        c3 += p * OPC[i][3];
    }
    return make_float4(c0, c1, c2, c3);
}

__device__ __forceinline__ uint2 pack_coef(float4 c) {
    uint2 r;
    r.x = __builtin_bit_cast(uint32_t, __floats2half2_rn(c.x, c.y));
    r.y = __builtin_bit_cast(uint32_t, __floats2half2_rn(c.z, c.w));
    return r;
}

// prep: bakes run-invariant metadata.
//  - For each LAYER-2 gate g (fusing layer 1 into it): the 4 x byte-offsets
//    of its two layer-1 parents, the parents' coef pairs, and its own coefs.
//  - For each LAYER-3 gate: packed h2 byte-offsets + own coefs.
// Layer-1 gates need no standalone record (recomputed inside layer 2).
__global__ __launch_bounds__(64) void prep_kernel(
    const float* __restrict__ w1, const float* __restrict__ w2,
    const float* __restrict__ w3,
    const int* __restrict__ ia1, const int* __restrict__ ib1,
    const int* __restrict__ ia2, const int* __restrict__ ib2,
    const int* __restrict__ ia3, const int* __restrict__ ib3,
    uint2* __restrict__ bcIdx, uint4* __restrict__ bcCoefAB,
    uint2* __restrict__ bcCoefO, uint32_t* __restrict__ d3Idx,
    uint2* __restrict__ d3Coef) {
    int G = blockIdx.x * 64 + threadIdx.x;  // grid = (D2 + D3) / 64
    if (G < D2) {
        int g = G;
        int pa = ia2[g], pb = ib2[g];
        float4 cO = softmax_coef(w2 + (size_t)g * 16);
        float4 cA = softmax_coef(w1 + (size_t)pa * 16);
        float4 cB = softmax_coef(w1 + (size_t)pb * 16);
        uint2 xi;
        xi.x = (uint32_t)(ia1[pa] << 3) | ((uint32_t)(ib1[pa] << 3) << 16);
        xi.y = (uint32_t)(ia1[pb] << 3) | ((uint32_t)(ib1[pb] << 3) << 16);
        bcIdx[g] = xi;
        uint2 a = pack_coef(cA), b = pack_coef(cB);
        bcCoefAB[g] = make_uint4(a.x, a.y, b.x, b.y);
        bcCoefO[g] = pack_coef(cO);
    } else {
        int g = G - D2;
        float4 cO = softmax_coef(w3 + (size_t)g * 16);
        d3Idx[g] = (uint32_t)(ia3[g] << 3) | ((uint32_t)(ib3[g] << 3) << 16);
        d3Coef[g] = pack_coef(cO);
    }
}

// One gate for 4 rows (2x half2); compact coefs (c0c1, c2c3) broadcast here.
// h = (c0 + c2*b) + a*(c1 + c3*b): 6 v_pk_fma_f16 + 4 broadcast ops.
__device__ __forceinline__ uint2 gate4(uint2 av, uint2 bv, uint2 cf) {
    __half2 p = __builtin_bit_cast(__half2, cf.x);  // (c0,c1)
    __half2 q = __builtin_bit_cast(__half2, cf.y);  // (c2,c3)
    __half2 c0 = __low2half2(p), c1 = __high2half2(p);
    __half2 c2 = __low2half2(q), c3 = __high2half2(q);
    __half2 a01 = __builtin_bit_cast(__half2, av.x);
    __half2 a23 = __builtin_bit_cast(__half2, av.y);
    __half2 b01 = __builtin_bit_cast(__half2, bv.x);
    __half2 b23 = __builtin_bit_cast(__half2, bv.y);
    __half2 h01 = __hfma2(a01, __hfma2(b01, c3, c1), __hfma2(b01, c2, c0));
    __half2 h23 = __hfma2(a23, __hfma2(b23, c3, c1), __hfma2(b23, c2, c0));
    uint2 r;
    r.x = __builtin_bit_cast(uint32_t, h01);
    r.y = __builtin_bit_cast(uint32_t, h23);
    return r;
}

// Fused kernel: layers 1+2 fused (layer-1 parents recomputed from xb; VALU is
// the idle pipe, LDS capacity the scarce one), then layer 3 + group-sum.
// One block = 4 batch rows, activations row-interleaved fp16 [gate][4 rows].
__global__ __launch_bounds__(1024, 8) void fused_kernel(
    const float* __restrict__ x, const uint2* __restrict__ bcIdx,
    const uint4* __restrict__ bcCoefAB, const uint2* __restrict__ bcCoefO,
    const uint32_t* __restrict__ d3Idx, const uint2* __restrict__ d3Coef,
    float* __restrict__ out) {
    extern __shared__ char sm[];
    uint2* xb = (uint2*)(sm + SM_XB);
    uint2* h2 = (uint2*)(sm + SM_H2);
    float* csum = (float*)(sm + SM_CSUM);

    const int t = threadIdx.x;
    const int rowbase = blockIdx.x << 2;

    // Stage A: 4 rows of x -> fp16, row-interleaved into xb.
    {
        const float* xp = x + (size_t)rowbase * D0 + t;
        float v0 = xp[0];
        float v1 = xp[D0];
        float v2 = xp[2 * D0];
        float v3 = xp[3 * D0];
        uint2 v;
        v.x = __builtin_bit_cast(uint32_t, __floats2half2_rn(v0, v1));
        v.y = __builtin_bit_cast(uint32_t, __floats2half2_rn(v2, v3));
        xb[t] = v;
    }
    if (t < 40) csum[t] = 0.f;
    __syncthreads();

    // Stage BC: fused layers 1+2. Per layer-2 gate: recompute both layer-1
    // parents from xb (4 random ds_read_b64, zero-add addressing), then the
    // layer-2 gate; write h2 sequentially.
    for (int k = 0; k < 8; ++k) {
        int g = t + (k << 10);
        uint2 xi = bcIdx[g];
        uint4 cab = bcCoefAB[g];
        uint2 co = bcCoefO[g];
        uint2 aa = *(const uint2*)(sm + (xi.x & 0xffffu));
        uint2 ab = *(const uint2*)(sm + (xi.x >> 16));
        uint2 ba = *(const uint2*)(sm + (xi.y & 0xffffu));
        uint2 bb = *(const uint2*)(sm + (xi.y >> 16));
        uint2 ha = gate4(aa, ab, make_uint2(cab.x, cab.y));
        uint2 hb = gate4(ba, bb, make_uint2(cab.z, cab.w));
        h2[g] = gate4(ha, hb, co);
    }
    __syncthreads();

    // Stage D: layer 3 + grouped sum. Each wave owns 640 contiguous gates
    // (spans <=2 classes; 64-gate chunks never straddle a class boundary).
    {
        const int wv = t >> 6, lane = t & 63;
        const int gbase = wv * 640;
        const int cA = gbase >> 10;
        const int bnd = (cA + 1) << 10;
        float s0[4] = {0.f, 0.f, 0.f, 0.f};
        float s1[4] = {0.f, 0.f, 0.f, 0.f};
#pragma unroll
        for (int j = 0; j < 10; ++j) {
            int gc = gbase + (j << 6);
            int g = gc + lane;
            uint32_t ip = d3Idx[g];
            uint2 cf = d3Coef[g];
            uint2 av = *(const uint2*)(sm + SM_H2 + (ip & 0xffffu));
            uint2 bv = *(const uint2*)(sm + SM_H2 + (ip >> 16));
            uint2 hv = gate4(av, bv, cf);
            __half2 h01 = __builtin_bit_cast(__half2, hv.x);
            __half2 h23 = __builtin_bit_cast(__half2, hv.y);
            float f0 = __low2float(h01), f1 = __high2float(h01);
            float f2 = __low2float(h23), f3 = __high2float(h23);
            if (gc < bnd) {
                s0[0] += f0; s0[1] += f1; s0[2] += f2; s0[3] += f3;
            } else {
                s1[0] += f0; s1[1] += f1; s1[2] += f2; s1[3] += f3;
            }
        }
#pragma unroll
        for (int m = 1; m < 64; m <<= 1) {
#pragma unroll
            for (int r = 0; r < 4; ++r) {
                s0[r] += __shfl_xor(s0[r], m, 64);
                s1[r] += __shfl_xor(s1[r], m, 64);
            }
        }
        if (lane == 0) {
#pragma unroll
            for (int r = 0; r < 4; ++r) atomicAdd(&csum[cA * 4 + r], s0[r]);
            if (gbase + 640 > bnd) {
#pragma unroll
                for (int r = 0; r < 4; ++r) atomicAdd(&csum[(cA + 1) * 4 + r], s1[r]);
            }
        }
    }
    __syncthreads();

    if (t < 40) {
        int c = t >> 2, r = t & 3;
        out[(size_t)(rowbase + r) * 10 + c] = csum[t] * (1.0f / 30.0f);
    }
}

extern "C" void kernel_launch(void* const* d_in, const int* in_sizes, int n_in,
                              void* d_out, int out_size, void* d_ws, size_t ws_size,
                              hipStream_t stream) {
    const float* x = (const float*)d_in[0];
    const float* w1 = (const float*)d_in[1];
    const float* w2 = (const float*)d_in[2];
    const float* w3 = (const float*)d_in[3];
    const int* ia1 = (const int*)d_in[4];
    const int* ib1 = (const int*)d_in[5];
    const int* ia2 = (const int*)d_in[6];
    const int* ib2 = (const int*)d_in[7];
    const int* ia3 = (const int*)d_in[8];
    const int* ib3 = (const int*)d_in[9];
    float* out = (float*)d_out;

    // Workspace: bcIdx 64K | bcCoefAB 128K | bcCoefO 64K | d3Idx 40K | d3Coef 80K
    char* p = (char*)d_ws;
    uint2* bcIdx = (uint2*)p;                 p += (size_t)D2 * 8;
    uint4* bcCoefAB = (uint4*)p;              p += (size_t)D2 * 16;
    uint2* bcCoefO = (uint2*)p;               p += (size_t)D2 * 8;
    uint32_t* d3Idx = (uint32_t*)p;           p += (size_t)D3 * 4;
    uint2* d3Coef = (uint2*)p;

    // >64KB dynamic LDS opt-in (host-side; graph-capture safe).
    hipFuncSetAttribute(reinterpret_cast<const void*>(fused_kernel),
                        hipFuncAttributeMaxDynamicSharedMemorySize, SM_BYTES);

    prep_kernel<<<(D2 + D3) / 64, 64, 0, stream>>>(
        w1, w2, w3, ia1, ib1, ia2, ib2, ia3, ib3,
        bcIdx, bcCoefAB, bcCoefO, d3Idx, d3Coef);
    fused_kernel<<<B_ROWS / 4, 1024, SM_BYTES, stream>>>(
        x, bcIdx, bcCoefAB, bcCoefO, d3Idx, d3Coef, out);
}